// Round 2
// baseline (1664.106 us; speedup 1.0000x reference)
//
#include <hip/hip_runtime.h>

#define NH 3
#define HID 8
#define C1 24   // NH*HID
#define C2 16
#define BSH 7          // 128 nodes per bucket
#define BNODES 128
#define NBMAX 800      // actual NB = ceil(100000/128) = 782
#define PCHUNK 16384   // edges per partition block

// ---------------- layer-1 projection: z1[N][24], f1s/f1d[N][4] ----------------
__global__ __launch_bounds__(256) void k_z1(
    const float* __restrict__ emb, const float* __restrict__ W1g,
    const float* __restrict__ a1g, float* __restrict__ z1,
    float4* __restrict__ f1s, float4* __restrict__ f1d, int N) {
    __shared__ float sW[NH * 64 * HID];   // [h][d][o]
    __shared__ float sa[NH * 2 * HID];
    for (int i = threadIdx.x; i < NH * 64 * HID; i += blockDim.x) sW[i] = W1g[i];
    for (int i = threadIdx.x; i < NH * 2 * HID; i += blockDim.x) sa[i] = a1g[i];
    __syncthreads();
    int n = blockIdx.x * blockDim.x + threadIdx.x;
    if (n >= N) return;
    float e[64];
    const float4* ep = (const float4*)(emb + (size_t)n * 64);
#pragma unroll
    for (int i = 0; i < 16; ++i) {
        float4 v = ep[i];
        e[4*i+0] = v.x; e[4*i+1] = v.y; e[4*i+2] = v.z; e[4*i+3] = v.w;
    }
    float z[C1];
#pragma unroll
    for (int c = 0; c < C1; ++c) z[c] = 0.f;
    for (int d = 0; d < 64; ++d) {
        float ed = e[d];
#pragma unroll
        for (int h = 0; h < NH; ++h) {
            const float4* wp = (const float4*)&sW[(h * 64 + d) * HID];
            float4 w0 = wp[0], w1 = wp[1];
            z[h*HID+0] += ed * w0.x; z[h*HID+1] += ed * w0.y;
            z[h*HID+2] += ed * w0.z; z[h*HID+3] += ed * w0.w;
            z[h*HID+4] += ed * w1.x; z[h*HID+5] += ed * w1.y;
            z[h*HID+6] += ed * w1.z; z[h*HID+7] += ed * w1.w;
        }
    }
    float4* zp = (float4*)(z1 + (size_t)n * C1);
#pragma unroll
    for (int i = 0; i < 6; ++i)
        zp[i] = make_float4(z[4*i], z[4*i+1], z[4*i+2], z[4*i+3]);
    float fs[NH], fd[NH];
#pragma unroll
    for (int h = 0; h < NH; ++h) {
        float s = 0.f, dsum = 0.f;
#pragma unroll
        for (int o = 0; o < HID; ++o) {
            s    += z[h*HID+o] * sa[h*2*HID + o];
            dsum += z[h*HID+o] * sa[h*2*HID + HID + o];
        }
        fs[h] = s; fd[h] = dsum;
    }
    f1s[n] = make_float4(fs[0], fs[1], fs[2], 0.f);
    f1d[n] = make_float4(fd[0], fd[1], fd[2], 0.f);
}

// ---------------- bucket partition (radix by dst>>7) ----------------
__global__ void k_zero(int* __restrict__ p, int n) {
    int i = blockIdx.x * blockDim.x + threadIdx.x;
    if (i < n) p[i] = 0;
}

__global__ __launch_bounds__(256) void k_count(const int* __restrict__ dst,
                                               int* __restrict__ bcnt, int E, int NB) {
    __shared__ int lh[NBMAX];
    for (int i = threadIdx.x; i < NB; i += 256) lh[i] = 0;
    __syncthreads();
    int base = blockIdx.x * PCHUNK;
    int end = base + PCHUNK; if (end > E) end = E;
    for (int i = base + threadIdx.x; i < end; i += 256)
        atomicAdd(&lh[dst[i] >> BSH], 1);
    __syncthreads();
    for (int i = threadIdx.x; i < NB; i += 256)
        if (lh[i]) atomicAdd(&bcnt[i], lh[i]);
}

__global__ __launch_bounds__(256) void k_bscan(const int* __restrict__ bcnt,
                                               int* __restrict__ boff,
                                               int* __restrict__ bcur, int NB) {
    __shared__ int sd[256];
    int tid = threadIdx.x;
    int g0 = tid * 4;
    int v[4];
#pragma unroll
    for (int i = 0; i < 4; ++i) { int g = g0 + i; v[i] = (g < NB) ? bcnt[g] : 0; }
    int tsum = v[0] + v[1] + v[2] + v[3];
    sd[tid] = tsum; __syncthreads();
    for (int off = 1; off < 256; off <<= 1) {
        int t = (tid >= off) ? sd[tid - off] : 0;
        __syncthreads();
        sd[tid] += t;
        __syncthreads();
    }
    int pref = sd[tid] - tsum;
#pragma unroll
    for (int i = 0; i < 4; ++i) {
        int g = g0 + i;
        if (g < NB) {
            boff[g] = pref; bcur[g] = pref;
            if (g == NB - 1) boff[NB] = pref + v[i];
            pref += v[i];
        }
    }
}

__global__ __launch_bounds__(256) void k_part(const int* __restrict__ src,
                                              const int* __restrict__ dst,
                                              int* __restrict__ bcur,
                                              int* __restrict__ bedges, int E, int NB) {
    __shared__ int lh[NBMAX];
    __shared__ int lbase[NBMAX];
    for (int i = threadIdx.x; i < NB; i += 256) lh[i] = 0;
    __syncthreads();
    int base = blockIdx.x * PCHUNK;
    int end = base + PCHUNK; if (end > E) end = E;
    for (int i = base + threadIdx.x; i < end; i += 256)
        atomicAdd(&lh[dst[i] >> BSH], 1);
    __syncthreads();
    for (int i = threadIdx.x; i < NB; i += 256) {
        int c = lh[i];
        lbase[i] = c ? atomicAdd(&bcur[i], c) : 0;
        lh[i] = 0;
    }
    __syncthreads();
    for (int i = base + threadIdx.x; i < end; i += 256) {
        int d = dst[i];
        int b = d >> BSH;
        int p = lbase[b] + atomicAdd(&lh[b], 1);
        bedges[p] = src[i] | ((d & (BNODES - 1)) << 17);
    }
}

// ---------------- GAT layer 1: one block per bucket, LDS accumulate ----------------
__global__ __launch_bounds__(256) void k_gat1b(
    const int* __restrict__ boff, const int* __restrict__ bedges,
    const float* __restrict__ z1, const float4* __restrict__ f1s,
    const float4* __restrict__ f1d,
    const float* __restrict__ W2g, const float* __restrict__ a2g,
    float* __restrict__ z2, float* __restrict__ f2s, float* __restrict__ f2d, int N) {
    __shared__ float sacc[BNODES][C1 + NH];   // 128 x 27: 24 acc + 3 den
    __shared__ float sfd[BNODES][NH];
    __shared__ float sW2[C1 * C2];
    __shared__ float sa2[2 * C2];
    int tid = threadIdx.x;
    for (int i = tid; i < BNODES * (C1 + NH); i += 256) ((float*)sacc)[i] = 0.f;
    for (int i = tid; i < C1 * C2; i += 256) sW2[i] = W2g[i];
    if (tid < 2 * C2) sa2[tid] = a2g[tid];
    int n0 = blockIdx.x << BSH;
    if (tid < BNODES) {
        int n = n0 + tid;
        if (n < N) {
            float4 f = f1d[n];
            sfd[tid][0] = f.x; sfd[tid][1] = f.y; sfd[tid][2] = f.z;
        }
    }
    __syncthreads();
    int beg = boff[blockIdx.x], end = boff[blockIdx.x + 1];
    for (int i = beg + tid; i < end; i += 256) {
        int pk = bedges[i];
        int s = pk & 0x1FFFF;
        int d7 = pk >> 17;
        float4 fsv = f1s[s];
        float e0 = fsv.x + sfd[d7][0];
        float e1 = fsv.y + sfd[d7][1];
        float e2 = fsv.z + sfd[d7][2];
        e0 = e0 > 0.f ? e0 : 0.01f * e0;
        e1 = e1 > 0.f ? e1 : 0.01f * e1;
        e2 = e2 > 0.f ? e2 : 0.01f * e2;
        float a0 = __expf(e0), a1 = __expf(e1), a2v = __expf(e2);
        atomicAdd(&sacc[d7][C1 + 0], a0);
        atomicAdd(&sacc[d7][C1 + 1], a1);
        atomicAdd(&sacc[d7][C1 + 2], a2v);
        const float4* zp = (const float4*)(z1 + (size_t)s * C1);
        float4 q0 = zp[0], q1 = zp[1], q2 = zp[2], q3 = zp[3], q4 = zp[4], q5 = zp[5];
        atomicAdd(&sacc[d7][0],  a0 * q0.x); atomicAdd(&sacc[d7][1],  a0 * q0.y);
        atomicAdd(&sacc[d7][2],  a0 * q0.z); atomicAdd(&sacc[d7][3],  a0 * q0.w);
        atomicAdd(&sacc[d7][4],  a0 * q1.x); atomicAdd(&sacc[d7][5],  a0 * q1.y);
        atomicAdd(&sacc[d7][6],  a0 * q1.z); atomicAdd(&sacc[d7][7],  a0 * q1.w);
        atomicAdd(&sacc[d7][8],  a1 * q2.x); atomicAdd(&sacc[d7][9],  a1 * q2.y);
        atomicAdd(&sacc[d7][10], a1 * q2.z); atomicAdd(&sacc[d7][11], a1 * q2.w);
        atomicAdd(&sacc[d7][12], a1 * q3.x); atomicAdd(&sacc[d7][13], a1 * q3.y);
        atomicAdd(&sacc[d7][14], a1 * q3.z); atomicAdd(&sacc[d7][15], a1 * q3.w);
        atomicAdd(&sacc[d7][16], a2v * q4.x); atomicAdd(&sacc[d7][17], a2v * q4.y);
        atomicAdd(&sacc[d7][18], a2v * q4.z); atomicAdd(&sacc[d7][19], a2v * q4.w);
        atomicAdd(&sacc[d7][20], a2v * q5.x); atomicAdd(&sacc[d7][21], a2v * q5.y);
        atomicAdd(&sacc[d7][22], a2v * q5.z); atomicAdd(&sacc[d7][23], a2v * q5.w);
    }
    __syncthreads();
    if (tid < BNODES) {
        int n = n0 + tid;
        if (n < N) {
            float h1v[C1];
#pragma unroll
            for (int h = 0; h < NH; ++h) {
                float inv = 1.f / sacc[tid][C1 + h];
#pragma unroll
                for (int o = 0; o < HID; ++o) {
                    float v = sacc[tid][h * HID + o] * inv;
                    h1v[h * HID + o] = v > 0.f ? v : (__expf(v) - 1.f);
                }
            }
            float zz[C2];
#pragma unroll
            for (int k = 0; k < C2; ++k) zz[k] = 0.f;
            for (int c = 0; c < C1; ++c) {
                float hv = h1v[c];
#pragma unroll
                for (int k = 0; k < C2; ++k) zz[k] += hv * sW2[c * C2 + k];
            }
            float fs = 0.f, fdd = 0.f;
#pragma unroll
            for (int k = 0; k < C2; ++k) {
                fs  += zz[k] * sa2[k];
                fdd += zz[k] * sa2[C2 + k];
            }
            float4* zo = (float4*)(z2 + (size_t)n * C2);
#pragma unroll
            for (int i = 0; i < 4; ++i)
                zo[i] = make_float4(zz[4*i], zz[4*i+1], zz[4*i+2], zz[4*i+3]);
            f2s[n] = fs;
            f2d[n] = fdd;
        }
    }
}

// ---------------- GAT layer 2: one block per bucket ----------------
__global__ __launch_bounds__(256) void k_gat2b(
    const int* __restrict__ boff, const int* __restrict__ bedges,
    const float* __restrict__ z2, const float* __restrict__ f2s,
    const float* __restrict__ f2d, float* __restrict__ item, int N) {
    __shared__ float sacc[BNODES][C2 + 1];   // 128 x 17: 16 acc + den
    __shared__ float sfd2[BNODES];
    int tid = threadIdx.x;
    for (int i = tid; i < BNODES * (C2 + 1); i += 256) ((float*)sacc)[i] = 0.f;
    int n0 = blockIdx.x << BSH;
    if (tid < BNODES) {
        int n = n0 + tid;
        if (n < N) sfd2[tid] = f2d[n];
    }
    __syncthreads();
    int beg = boff[blockIdx.x], end = boff[blockIdx.x + 1];
    for (int i = beg + tid; i < end; i += 256) {
        int pk = bedges[i];
        int s = pk & 0x1FFFF;
        int d7 = pk >> 17;
        float e = f2s[s] + sfd2[d7];
        e = e > 0.f ? e : 0.01f * e;
        float a = __expf(e);
        atomicAdd(&sacc[d7][C2], a);
        const float4* zp = (const float4*)(z2 + (size_t)s * C2);
        float4 q0 = zp[0], q1 = zp[1], q2 = zp[2], q3 = zp[3];
        atomicAdd(&sacc[d7][0],  a * q0.x); atomicAdd(&sacc[d7][1],  a * q0.y);
        atomicAdd(&sacc[d7][2],  a * q0.z); atomicAdd(&sacc[d7][3],  a * q0.w);
        atomicAdd(&sacc[d7][4],  a * q1.x); atomicAdd(&sacc[d7][5],  a * q1.y);
        atomicAdd(&sacc[d7][6],  a * q1.z); atomicAdd(&sacc[d7][7],  a * q1.w);
        atomicAdd(&sacc[d7][8],  a * q2.x); atomicAdd(&sacc[d7][9],  a * q2.y);
        atomicAdd(&sacc[d7][10], a * q2.z); atomicAdd(&sacc[d7][11], a * q2.w);
        atomicAdd(&sacc[d7][12], a * q3.x); atomicAdd(&sacc[d7][13], a * q3.y);
        atomicAdd(&sacc[d7][14], a * q3.z); atomicAdd(&sacc[d7][15], a * q3.w);
    }
    __syncthreads();
    if (tid < BNODES) {
        int n = n0 + tid;
        if (n < N) {
            float inv = 1.f / sacc[tid][C2];
            float4* io = (float4*)(item + (size_t)n * C2);
#pragma unroll
            for (int i = 0; i < 4; ++i)
                io[i] = make_float4(sacc[tid][4*i] * inv, sacc[tid][4*i+1] * inv,
                                    sacc[tid][4*i+2] * inv, sacc[tid][4*i+3] * inv);
        }
    }
}

// ---------------- query pooling: one block per query row ----------------
__global__ __launch_bounds__(256) void k_query(
    const float* __restrict__ queries, const float* __restrict__ item,
    float* __restrict__ out, int N) {
    int b = blockIdx.x;
    const float4* qrow = (const float4*)(queries + (size_t)b * N);
    int n4 = N >> 2;
    float acc[C2];
#pragma unroll
    for (int k = 0; k < C2; ++k) acc[k] = 0.f;
    float cnt = 0.f;
    for (int i = threadIdx.x; i < n4; i += 256) {
        float4 v = qrow[i];
        int j = i * 4;
        float vv[4] = {v.x, v.y, v.z, v.w};
#pragma unroll
        for (int c = 0; c < 4; ++c) {
            if (vv[c] != 0.f) {
                cnt += vv[c];
                const float4* rp = (const float4*)(item + (size_t)(j + c) * C2);
                float4 r0 = rp[0], r1 = rp[1], r2 = rp[2], r3 = rp[3];
                acc[0]  += vv[c]*r0.x; acc[1]  += vv[c]*r0.y; acc[2]  += vv[c]*r0.z; acc[3]  += vv[c]*r0.w;
                acc[4]  += vv[c]*r1.x; acc[5]  += vv[c]*r1.y; acc[6]  += vv[c]*r1.z; acc[7]  += vv[c]*r1.w;
                acc[8]  += vv[c]*r2.x; acc[9]  += vv[c]*r2.y; acc[10] += vv[c]*r2.z; acc[11] += vv[c]*r2.w;
                acc[12] += vv[c]*r3.x; acc[13] += vv[c]*r3.y; acc[14] += vv[c]*r3.z; acc[15] += vv[c]*r3.w;
            }
        }
    }
    int rem = N & 3;
    if ((int)threadIdx.x < rem) {
        int j = n4 * 4 + threadIdx.x;
        float qv = queries[(size_t)b * N + j];
        if (qv != 0.f) {
            cnt += qv;
#pragma unroll
            for (int k = 0; k < C2; ++k) acc[k] += qv * item[(size_t)j * C2 + k];
        }
    }
    __shared__ float red[4][C2 + 1];
    int lane = threadIdx.x & 63, wid = threadIdx.x >> 6;
#pragma unroll
    for (int k = 0; k < C2; ++k)
        for (int off = 32; off; off >>= 1) acc[k] += __shfl_down(acc[k], off, 64);
    for (int off = 32; off; off >>= 1) cnt += __shfl_down(cnt, off, 64);
    if (lane == 0) {
#pragma unroll
        for (int k = 0; k < C2; ++k) red[wid][k] = acc[k];
        red[wid][C2] = cnt;
    }
    __syncthreads();
    if (threadIdx.x < C2 + 1) {
        float s = red[0][threadIdx.x] + red[1][threadIdx.x] +
                  red[2][threadIdx.x] + red[3][threadIdx.x];
        red[0][threadIdx.x] = s;
    }
    __syncthreads();
    if (threadIdx.x < C2)
        out[(size_t)b * C2 + threadIdx.x] = red[0][threadIdx.x] / red[0][C2];
}

// ---------------- pos/neg gathers ----------------
__global__ void k_posneg(const int* __restrict__ pos, const int* __restrict__ neg,
                         const float* __restrict__ item, float* __restrict__ out, int B) {
    int idx = blockIdx.x * blockDim.x + threadIdx.x;
    int total = 2 * B * C2;
    if (idx >= total) return;
    int which = idx / (B * C2);
    int r = idx - which * B * C2;
    int b = r / C2, k = r - b * C2;
    int node = which ? neg[b] : pos[b];
    out[(size_t)B * C2 + idx] = item[(size_t)node * C2 + k];
}

extern "C" void kernel_launch(void* const* d_in, const int* in_sizes, int n_in,
                              void* d_out, int out_size, void* d_ws, size_t ws_size,
                              hipStream_t stream) {
    const float* queries = (const float*)d_in[0];
    const int*   pos     = (const int*)d_in[1];
    const int*   neg     = (const int*)d_in[2];
    const float* emb     = (const float*)d_in[3];
    const float* W1      = (const float*)d_in[4];
    const float* a1      = (const float*)d_in[5];
    const float* W2      = (const float*)d_in[6];
    const float* a2      = (const float*)d_in[7];
    const int*   src     = (const int*)d_in[8];
    const int*   dst     = (const int*)d_in[9];

    int B = in_sizes[1];
    int N = in_sizes[3] / 64;
    int E = in_sizes[8];
    float* out = (float*)d_out;

    int NB = (N + BNODES - 1) >> BSH;

    char* w = (char*)d_ws;
    auto alloc = [&](size_t bytes) -> char* {
        char* p = w;
        w += (bytes + 255) & ~(size_t)255;
        return p;
    };
    float*  z1     = (float*)alloc(sizeof(float) * (size_t)N * C1);
    float4* f1s    = (float4*)alloc(sizeof(float4) * (size_t)N);
    float4* f1d    = (float4*)alloc(sizeof(float4) * (size_t)N);
    float*  z2     = (float*)alloc(sizeof(float) * (size_t)N * C2);
    float*  f2s    = (float*)alloc(sizeof(float) * (size_t)N);
    float*  f2d    = (float*)alloc(sizeof(float) * (size_t)N);
    float*  item   = (float*)alloc(sizeof(float) * (size_t)N * C2);
    int*    bcnt   = (int*)alloc(sizeof(int) * (size_t)NB);
    int*    boff   = (int*)alloc(sizeof(int) * (size_t)(NB + 1));
    int*    bcur   = (int*)alloc(sizeof(int) * (size_t)NB);
    int*    bedges = (int*)alloc(sizeof(int) * (size_t)E);

    int nblkN = (N + 255) / 256;
    int nPart = (E + PCHUNK - 1) / PCHUNK;

    k_z1<<<nblkN, 256, 0, stream>>>(emb, W1, a1, z1, f1s, f1d, N);
    k_zero<<<(NB + 255) / 256, 256, 0, stream>>>(bcnt, NB);
    k_count<<<nPart, 256, 0, stream>>>(dst, bcnt, E, NB);
    k_bscan<<<1, 256, 0, stream>>>(bcnt, boff, bcur, NB);
    k_part<<<nPart, 256, 0, stream>>>(src, dst, bcur, bedges, E, NB);
    k_gat1b<<<NB, 256, 0, stream>>>(boff, bedges, z1, f1s, f1d, W2, a2, z2, f2s, f2d, N);
    k_gat2b<<<NB, 256, 0, stream>>>(boff, bedges, z2, f2s, f2d, item, N);
    k_query<<<B, 256, 0, stream>>>(queries, item, out, N);
    k_posneg<<<(2 * B * C2 + 255) / 256, 256, 0, stream>>>(pos, neg, item, out, B);
}

// Round 3
// 880.832 us; speedup vs baseline: 1.8892x; 1.8892x over previous
//
#include <hip/hip_runtime.h>

#define NH 3
#define HID 8
#define C1 24   // NH*HID
#define C2 16
#define BSH 6          // 64 nodes per bucket
#define BNODES 64
#define NBMAX 1600     // actual NB = ceil(100000/64) = 1563
#define SCAP 3072      // max edges per bucket (mean 2112, sigma ~46)
#define PCHUNK 16384   // edges per partition block

// ---------------- layer-1 projection: z1[N][24], f1s/f1d[N][4] ----------------
__global__ __launch_bounds__(256) void k_z1(
    const float* __restrict__ emb, const float* __restrict__ W1g,
    const float* __restrict__ a1g, float* __restrict__ z1,
    float4* __restrict__ f1s, float4* __restrict__ f1d, int N) {
    __shared__ float sW[NH * 64 * HID];   // [h][d][o]
    __shared__ float sa[NH * 2 * HID];
    for (int i = threadIdx.x; i < NH * 64 * HID; i += blockDim.x) sW[i] = W1g[i];
    for (int i = threadIdx.x; i < NH * 2 * HID; i += blockDim.x) sa[i] = a1g[i];
    __syncthreads();
    int n = blockIdx.x * blockDim.x + threadIdx.x;
    if (n >= N) return;
    float e[64];
    const float4* ep = (const float4*)(emb + (size_t)n * 64);
#pragma unroll
    for (int i = 0; i < 16; ++i) {
        float4 v = ep[i];
        e[4*i+0] = v.x; e[4*i+1] = v.y; e[4*i+2] = v.z; e[4*i+3] = v.w;
    }
    float z[C1];
#pragma unroll
    for (int c = 0; c < C1; ++c) z[c] = 0.f;
    for (int d = 0; d < 64; ++d) {
        float ed = e[d];
#pragma unroll
        for (int h = 0; h < NH; ++h) {
            const float4* wp = (const float4*)&sW[(h * 64 + d) * HID];
            float4 w0 = wp[0], w1 = wp[1];
            z[h*HID+0] += ed * w0.x; z[h*HID+1] += ed * w0.y;
            z[h*HID+2] += ed * w0.z; z[h*HID+3] += ed * w0.w;
            z[h*HID+4] += ed * w1.x; z[h*HID+5] += ed * w1.y;
            z[h*HID+6] += ed * w1.z; z[h*HID+7] += ed * w1.w;
        }
    }
    float4* zp = (float4*)(z1 + (size_t)n * C1);
#pragma unroll
    for (int i = 0; i < 6; ++i)
        zp[i] = make_float4(z[4*i], z[4*i+1], z[4*i+2], z[4*i+3]);
    float fs[NH], fd[NH];
#pragma unroll
    for (int h = 0; h < NH; ++h) {
        float s = 0.f, dsum = 0.f;
#pragma unroll
        for (int o = 0; o < HID; ++o) {
            s    += z[h*HID+o] * sa[h*2*HID + o];
            dsum += z[h*HID+o] * sa[h*2*HID + HID + o];
        }
        fs[h] = s; fd[h] = dsum;
    }
    f1s[n] = make_float4(fs[0], fs[1], fs[2], 0.f);
    f1d[n] = make_float4(fd[0], fd[1], fd[2], 0.f);
}

// ---------------- bucket partition (radix by dst>>6) ----------------
__global__ void k_zero(int* __restrict__ p, int n) {
    int i = blockIdx.x * blockDim.x + threadIdx.x;
    if (i < n) p[i] = 0;
}

__global__ __launch_bounds__(256) void k_count(const int* __restrict__ dst,
                                               int* __restrict__ bcnt, int E, int NB) {
    __shared__ int lh[NBMAX];
    for (int i = threadIdx.x; i < NB; i += 256) lh[i] = 0;
    __syncthreads();
    int base = blockIdx.x * PCHUNK;
    int end = base + PCHUNK; if (end > E) end = E;
    for (int i = base + threadIdx.x; i < end; i += 256)
        atomicAdd(&lh[dst[i] >> BSH], 1);
    __syncthreads();
    for (int i = threadIdx.x; i < NB; i += 256)
        if (lh[i]) atomicAdd(&bcnt[i], lh[i]);
}

__global__ __launch_bounds__(256) void k_bscan(const int* __restrict__ bcnt,
                                               int* __restrict__ boff,
                                               int* __restrict__ bcur,
                                               int* __restrict__ rowptr,
                                               int NB, int N, int E) {
    __shared__ int sd[256];
    int tid = threadIdx.x;
    int v[8]; int tsum = 0;
#pragma unroll
    for (int i = 0; i < 8; ++i) {
        int g = tid * 8 + i;
        v[i] = (g < NB) ? bcnt[g] : 0;
        tsum += v[i];
    }
    sd[tid] = tsum; __syncthreads();
    for (int off = 1; off < 256; off <<= 1) {
        int t = (tid >= off) ? sd[tid - off] : 0;
        __syncthreads();
        sd[tid] += t;
        __syncthreads();
    }
    int pref = sd[tid] - tsum;
#pragma unroll
    for (int i = 0; i < 8; ++i) {
        int g = tid * 8 + i;
        if (g < NB) { boff[g] = pref; bcur[g] = pref; pref += v[i]; }
    }
    if (tid == 255) boff[NB] = pref;
    if (tid == 0) rowptr[N] = E;
}

__global__ __launch_bounds__(256) void k_part(const int* __restrict__ src,
                                              const int* __restrict__ dst,
                                              int* __restrict__ bcur,
                                              int* __restrict__ bedges, int E, int NB) {
    __shared__ int lh[NBMAX];
    __shared__ int lbase[NBMAX];
    for (int i = threadIdx.x; i < NB; i += 256) lh[i] = 0;
    __syncthreads();
    int base = blockIdx.x * PCHUNK;
    int end = base + PCHUNK; if (end > E) end = E;
    for (int i = base + threadIdx.x; i < end; i += 256)
        atomicAdd(&lh[dst[i] >> BSH], 1);
    __syncthreads();
    for (int i = threadIdx.x; i < NB; i += 256) {
        int c = lh[i];
        lbase[i] = c ? atomicAdd(&bcur[i], c) : 0;
        lh[i] = 0;
    }
    __syncthreads();
    for (int i = base + threadIdx.x; i < end; i += 256) {
        int d = dst[i];
        int b = d >> BSH;
        int p = lbase[b] + atomicAdd(&lh[b], 1);
        bedges[p] = src[i] | ((d & (BNODES - 1)) << 17);
    }
}

// --------- GAT layer 1: sort bucket in LDS, 4 threads/node, register acc ---------
__global__ __launch_bounds__(256) void k_gat1s(
    const int* __restrict__ boff, int* __restrict__ bedges,
    const float* __restrict__ z1, const float4* __restrict__ f1s,
    const float4* __restrict__ f1d,
    const float* __restrict__ W2g, const float* __restrict__ a2g,
    float* __restrict__ z2, float* __restrict__ f2s, float* __restrict__ f2d,
    int* __restrict__ rowptr, int N) {
    __shared__ int ssrc[SCAP];
    __shared__ int scnt[BNODES];
    __shared__ int sstart[BNODES + 1];
    __shared__ int scur[BNODES];
    __shared__ float sW2[C1 * C2];
    __shared__ float sa2[2 * C2];
    int tid = threadIdx.x;
    int b = blockIdx.x;
    int beg = boff[b], cnt = boff[b + 1] - beg;
    if (tid < BNODES) scnt[tid] = 0;
    for (int i = tid; i < C1 * C2; i += 256) sW2[i] = W2g[i];
    if (tid < 2 * C2) sa2[tid] = a2g[tid];
    __syncthreads();
    // count
    for (int i = tid; i < cnt; i += 256)
        atomicAdd(&scnt[bedges[beg + i] >> 17], 1);
    __syncthreads();
    // exclusive scan over 64 counters (wave 0)
    if (tid < 64) {
        int v = scnt[tid];
        int x = v;
        for (int d = 1; d < 64; d <<= 1) {
            int t = __shfl_up(x, d, 64);
            if (tid >= d) x += t;
        }
        sstart[tid] = x - v;
        scur[tid] = x - v;
        if (tid == 63) sstart[64] = x;
    }
    __syncthreads();
    // place (counting sort)
    for (int i = tid; i < cnt; i += 256) {
        int pk = bedges[beg + i];
        int p = atomicAdd(&scur[pk >> 17], 1);
        ssrc[p] = pk & 0x1FFFF;
    }
    __syncthreads();
    // write sorted CSR back in-place + rowptr
    for (int i = tid; i < cnt; i += 256) bedges[beg + i] = ssrc[i];
    int n0 = b << BSH;
    if (tid < BNODES) {
        int n = n0 + tid;
        if (n < N) rowptr[n] = beg + sstart[tid];
    }
    // aggregate: 4 threads per node
    int nl = tid >> 2, l4 = tid & 3;
    int n = n0 + nl;
    int s0 = sstart[nl], s1 = sstart[nl + 1];
    float4 fdv = (n < N) ? f1d[n] : make_float4(0.f, 0.f, 0.f, 0.f);
    float acc[C1];
#pragma unroll
    for (int c = 0; c < C1; ++c) acc[c] = 0.f;
    float den0 = 0.f, den1 = 0.f, den2 = 0.f;
    for (int i = s0 + l4; i < s1; i += 4) {
        int s = ssrc[i];
        float4 fsv = f1s[s];
        float e0 = fsv.x + fdv.x, e1 = fsv.y + fdv.y, e2 = fsv.z + fdv.z;
        e0 = e0 > 0.f ? e0 : 0.01f * e0;
        e1 = e1 > 0.f ? e1 : 0.01f * e1;
        e2 = e2 > 0.f ? e2 : 0.01f * e2;
        float a0 = __expf(e0), a1 = __expf(e1), a2v = __expf(e2);
        den0 += a0; den1 += a1; den2 += a2v;
        const float4* zp = (const float4*)(z1 + (size_t)s * C1);
        float4 q0 = zp[0], q1 = zp[1], q2 = zp[2], q3 = zp[3], q4 = zp[4], q5 = zp[5];
        acc[0]  += a0 * q0.x; acc[1]  += a0 * q0.y; acc[2]  += a0 * q0.z; acc[3]  += a0 * q0.w;
        acc[4]  += a0 * q1.x; acc[5]  += a0 * q1.y; acc[6]  += a0 * q1.z; acc[7]  += a0 * q1.w;
        acc[8]  += a1 * q2.x; acc[9]  += a1 * q2.y; acc[10] += a1 * q2.z; acc[11] += a1 * q2.w;
        acc[12] += a1 * q3.x; acc[13] += a1 * q3.y; acc[14] += a1 * q3.z; acc[15] += a1 * q3.w;
        acc[16] += a2v * q4.x; acc[17] += a2v * q4.y; acc[18] += a2v * q4.z; acc[19] += a2v * q4.w;
        acc[20] += a2v * q5.x; acc[21] += a2v * q5.y; acc[22] += a2v * q5.z; acc[23] += a2v * q5.w;
    }
    // combine the 4 threads of each node (lanes 4k..4k+3, same wave)
#pragma unroll
    for (int c = 0; c < C1; ++c) {
        acc[c] += __shfl_xor(acc[c], 1, 64);
        acc[c] += __shfl_xor(acc[c], 2, 64);
    }
    den0 += __shfl_xor(den0, 1, 64); den0 += __shfl_xor(den0, 2, 64);
    den1 += __shfl_xor(den1, 1, 64); den1 += __shfl_xor(den1, 2, 64);
    den2 += __shfl_xor(den2, 1, 64); den2 += __shfl_xor(den2, 2, 64);
    if (l4 == 0 && n < N) {
        float h1v[C1];
        float inv0 = 1.f / den0, inv1 = 1.f / den1, inv2 = 1.f / den2;
#pragma unroll
        for (int o = 0; o < HID; ++o) {
            float v0 = acc[o] * inv0;
            float v1 = acc[HID + o] * inv1;
            float v2 = acc[2 * HID + o] * inv2;
            h1v[o]           = v0 > 0.f ? v0 : (__expf(v0) - 1.f);
            h1v[HID + o]     = v1 > 0.f ? v1 : (__expf(v1) - 1.f);
            h1v[2 * HID + o] = v2 > 0.f ? v2 : (__expf(v2) - 1.f);
        }
        float zz[C2];
#pragma unroll
        for (int k = 0; k < C2; ++k) zz[k] = 0.f;
        for (int c = 0; c < C1; ++c) {
            float hv = h1v[c];
#pragma unroll
            for (int k = 0; k < C2; ++k) zz[k] += hv * sW2[c * C2 + k];
        }
        float fs = 0.f, fdd = 0.f;
#pragma unroll
        for (int k = 0; k < C2; ++k) {
            fs  += zz[k] * sa2[k];
            fdd += zz[k] * sa2[C2 + k];
        }
        float4* zo = (float4*)(z2 + (size_t)n * C2);
#pragma unroll
        for (int i = 0; i < 4; ++i)
            zo[i] = make_float4(zz[4*i], zz[4*i+1], zz[4*i+2], zz[4*i+3]);
        f2s[n] = fs;
        f2d[n] = fdd;
    }
}

// --------- GAT layer 2: CSR, 4 threads/node, register acc ---------
__global__ __launch_bounds__(256) void k_gat2(
    const int* __restrict__ rowptr, const int* __restrict__ csr,
    const float* __restrict__ z2, const float* __restrict__ f2s,
    const float* __restrict__ f2d, float* __restrict__ item, int N) {
    int t = blockIdx.x * blockDim.x + threadIdx.x;
    int n = t >> 2, l4 = t & 3;
    if (n >= N) return;
    int beg = rowptr[n], end = rowptr[n + 1];
    float fdv = f2d[n];
    float acc[C2];
#pragma unroll
    for (int k = 0; k < C2; ++k) acc[k] = 0.f;
    float den = 0.f;
    for (int i = beg + l4; i < end; i += 4) {
        int s = csr[i];
        float e = f2s[s] + fdv;
        e = e > 0.f ? e : 0.01f * e;
        float a = __expf(e);
        den += a;
        const float4* zp = (const float4*)(z2 + (size_t)s * C2);
        float4 q0 = zp[0], q1 = zp[1], q2 = zp[2], q3 = zp[3];
        acc[0]  += a * q0.x; acc[1]  += a * q0.y; acc[2]  += a * q0.z; acc[3]  += a * q0.w;
        acc[4]  += a * q1.x; acc[5]  += a * q1.y; acc[6]  += a * q1.z; acc[7]  += a * q1.w;
        acc[8]  += a * q2.x; acc[9]  += a * q2.y; acc[10] += a * q2.z; acc[11] += a * q2.w;
        acc[12] += a * q3.x; acc[13] += a * q3.y; acc[14] += a * q3.z; acc[15] += a * q3.w;
    }
#pragma unroll
    for (int k = 0; k < C2; ++k) {
        acc[k] += __shfl_xor(acc[k], 1, 64);
        acc[k] += __shfl_xor(acc[k], 2, 64);
    }
    den += __shfl_xor(den, 1, 64);
    den += __shfl_xor(den, 2, 64);
    if (l4 == 0) {
        float inv = 1.f / den;
        float4* io = (float4*)(item + (size_t)n * C2);
#pragma unroll
        for (int i = 0; i < 4; ++i)
            io[i] = make_float4(acc[4*i]*inv, acc[4*i+1]*inv, acc[4*i+2]*inv, acc[4*i+3]*inv);
    }
}

// ---------------- query pooling: one block per query row ----------------
__global__ __launch_bounds__(256) void k_query(
    const float* __restrict__ queries, const float* __restrict__ item,
    float* __restrict__ out, int N) {
    int b = blockIdx.x;
    const float4* qrow = (const float4*)(queries + (size_t)b * N);
    int n4 = N >> 2;
    float acc[C2];
#pragma unroll
    for (int k = 0; k < C2; ++k) acc[k] = 0.f;
    float cnt = 0.f;
    for (int i = threadIdx.x; i < n4; i += 256) {
        float4 v = qrow[i];
        int j = i * 4;
        float vv[4] = {v.x, v.y, v.z, v.w};
#pragma unroll
        for (int c = 0; c < 4; ++c) {
            if (vv[c] != 0.f) {
                cnt += vv[c];
                const float4* rp = (const float4*)(item + (size_t)(j + c) * C2);
                float4 r0 = rp[0], r1 = rp[1], r2 = rp[2], r3 = rp[3];
                acc[0]  += vv[c]*r0.x; acc[1]  += vv[c]*r0.y; acc[2]  += vv[c]*r0.z; acc[3]  += vv[c]*r0.w;
                acc[4]  += vv[c]*r1.x; acc[5]  += vv[c]*r1.y; acc[6]  += vv[c]*r1.z; acc[7]  += vv[c]*r1.w;
                acc[8]  += vv[c]*r2.x; acc[9]  += vv[c]*r2.y; acc[10] += vv[c]*r2.z; acc[11] += vv[c]*r2.w;
                acc[12] += vv[c]*r3.x; acc[13] += vv[c]*r3.y; acc[14] += vv[c]*r3.z; acc[15] += vv[c]*r3.w;
            }
        }
    }
    int rem = N & 3;
    if ((int)threadIdx.x < rem) {
        int j = n4 * 4 + threadIdx.x;
        float qv = queries[(size_t)b * N + j];
        if (qv != 0.f) {
            cnt += qv;
#pragma unroll
            for (int k = 0; k < C2; ++k) acc[k] += qv * item[(size_t)j * C2 + k];
        }
    }
    __shared__ float red[4][C2 + 1];
    int lane = threadIdx.x & 63, wid = threadIdx.x >> 6;
#pragma unroll
    for (int k = 0; k < C2; ++k)
        for (int off = 32; off; off >>= 1) acc[k] += __shfl_down(acc[k], off, 64);
    for (int off = 32; off; off >>= 1) cnt += __shfl_down(cnt, off, 64);
    if (lane == 0) {
#pragma unroll
        for (int k = 0; k < C2; ++k) red[wid][k] = acc[k];
        red[wid][C2] = cnt;
    }
    __syncthreads();
    if (threadIdx.x < C2 + 1) {
        float s = red[0][threadIdx.x] + red[1][threadIdx.x] +
                  red[2][threadIdx.x] + red[3][threadIdx.x];
        red[0][threadIdx.x] = s;
    }
    __syncthreads();
    if (threadIdx.x < C2)
        out[(size_t)b * C2 + threadIdx.x] = red[0][threadIdx.x] / red[0][C2];
}

// ---------------- pos/neg gathers ----------------
__global__ void k_posneg(const int* __restrict__ pos, const int* __restrict__ neg,
                         const float* __restrict__ item, float* __restrict__ out, int B) {
    int idx = blockIdx.x * blockDim.x + threadIdx.x;
    int total = 2 * B * C2;
    if (idx >= total) return;
    int which = idx / (B * C2);
    int r = idx - which * B * C2;
    int b = r / C2, k = r - b * C2;
    int node = which ? neg[b] : pos[b];
    out[(size_t)B * C2 + idx] = item[(size_t)node * C2 + k];
}

extern "C" void kernel_launch(void* const* d_in, const int* in_sizes, int n_in,
                              void* d_out, int out_size, void* d_ws, size_t ws_size,
                              hipStream_t stream) {
    const float* queries = (const float*)d_in[0];
    const int*   pos     = (const int*)d_in[1];
    const int*   neg     = (const int*)d_in[2];
    const float* emb     = (const float*)d_in[3];
    const float* W1      = (const float*)d_in[4];
    const float* a1      = (const float*)d_in[5];
    const float* W2      = (const float*)d_in[6];
    const float* a2      = (const float*)d_in[7];
    const int*   src     = (const int*)d_in[8];
    const int*   dst     = (const int*)d_in[9];

    int B = in_sizes[1];
    int N = in_sizes[3] / 64;
    int E = in_sizes[8];
    float* out = (float*)d_out;

    int NB = (N + BNODES - 1) >> BSH;

    char* w = (char*)d_ws;
    auto alloc = [&](size_t bytes) -> char* {
        char* p = w;
        w += (bytes + 255) & ~(size_t)255;
        return p;
    };
    float*  z1     = (float*)alloc(sizeof(float) * (size_t)N * C1);
    float4* f1s    = (float4*)alloc(sizeof(float4) * (size_t)N);
    float4* f1d    = (float4*)alloc(sizeof(float4) * (size_t)N);
    float*  z2     = (float*)alloc(sizeof(float) * (size_t)N * C2);
    float*  f2s    = (float*)alloc(sizeof(float) * (size_t)N);
    float*  f2d    = (float*)alloc(sizeof(float) * (size_t)N);
    float*  item   = (float*)alloc(sizeof(float) * (size_t)N * C2);
    int*    bcnt   = (int*)alloc(sizeof(int) * (size_t)NB);
    int*    boff   = (int*)alloc(sizeof(int) * (size_t)(NB + 1));
    int*    bcur   = (int*)alloc(sizeof(int) * (size_t)NB);
    int*    rowptr = (int*)alloc(sizeof(int) * (size_t)(N + 1));
    int*    bedges = (int*)alloc(sizeof(int) * (size_t)E);

    int nblkN = (N + 255) / 256;
    int nPart = (E + PCHUNK - 1) / PCHUNK;

    k_z1<<<nblkN, 256, 0, stream>>>(emb, W1, a1, z1, f1s, f1d, N);
    k_zero<<<(NB + 255) / 256, 256, 0, stream>>>(bcnt, NB);
    k_count<<<nPart, 256, 0, stream>>>(dst, bcnt, E, NB);
    k_bscan<<<1, 256, 0, stream>>>(bcnt, boff, bcur, rowptr, NB, N, E);
    k_part<<<nPart, 256, 0, stream>>>(src, dst, bcur, bedges, E, NB);
    k_gat1s<<<NB, 256, 0, stream>>>(boff, bedges, z1, f1s, f1d, W2, a2,
                                    z2, f2s, f2d, rowptr, N);
    k_gat2<<<(N * 4 + 255) / 256, 256, 0, stream>>>(rowptr, bedges, z2, f2s, f2d, item, N);
    k_query<<<B, 256, 0, stream>>>(queries, item, out, N);
    k_posneg<<<(2 * B * C2 + 255) / 256, 256, 0, stream>>>(pos, neg, item, out, B);
}

// Round 4
// 857.024 us; speedup vs baseline: 1.9417x; 1.0278x over previous
//
#include <hip/hip_runtime.h>

#define NH 3
#define HID 8
#define C1 24   // NH*HID
#define C2 16
#define BSH 5          // 32 nodes per bucket
#define BNODES 32
#define NBMAX 3200     // actual NB = 100000/32 = 3125
#define SCAP 1792      // max edges per bucket (mean 1056)
#define PCHUNK 16384   // edges per partition block
#define AZS 32         // az1 row stride in floats (128B)

// ------- layer-1 projection: az1[N][32] = [f1s(3),pad,z1(24),pad(4)], f1d[N] -------
__global__ __launch_bounds__(256) void k_z1(
    const float* __restrict__ emb, const float* __restrict__ W1g,
    const float* __restrict__ a1g, float* __restrict__ az1,
    float4* __restrict__ f1d, int N) {
    __shared__ float sW[NH * 64 * HID];   // [h][d][o]
    __shared__ float sa[NH * 2 * HID];
    for (int i = threadIdx.x; i < NH * 64 * HID; i += blockDim.x) sW[i] = W1g[i];
    for (int i = threadIdx.x; i < NH * 2 * HID; i += blockDim.x) sa[i] = a1g[i];
    __syncthreads();
    int n = blockIdx.x * blockDim.x + threadIdx.x;
    if (n >= N) return;
    float e[64];
    const float4* ep = (const float4*)(emb + (size_t)n * 64);
#pragma unroll
    for (int i = 0; i < 16; ++i) {
        float4 v = ep[i];
        e[4*i+0] = v.x; e[4*i+1] = v.y; e[4*i+2] = v.z; e[4*i+3] = v.w;
    }
    float z[C1];
#pragma unroll
    for (int c = 0; c < C1; ++c) z[c] = 0.f;
    for (int d = 0; d < 64; ++d) {
        float ed = e[d];
#pragma unroll
        for (int h = 0; h < NH; ++h) {
            const float4* wp = (const float4*)&sW[(h * 64 + d) * HID];
            float4 w0 = wp[0], w1 = wp[1];
            z[h*HID+0] += ed * w0.x; z[h*HID+1] += ed * w0.y;
            z[h*HID+2] += ed * w0.z; z[h*HID+3] += ed * w0.w;
            z[h*HID+4] += ed * w1.x; z[h*HID+5] += ed * w1.y;
            z[h*HID+6] += ed * w1.z; z[h*HID+7] += ed * w1.w;
        }
    }
    float fs[NH], fd[NH];
#pragma unroll
    for (int h = 0; h < NH; ++h) {
        float s = 0.f, dsum = 0.f;
#pragma unroll
        for (int o = 0; o < HID; ++o) {
            s    += z[h*HID+o] * sa[h*2*HID + o];
            dsum += z[h*HID+o] * sa[h*2*HID + HID + o];
        }
        fs[h] = s; fd[h] = dsum;
    }
    float4* zp = (float4*)(az1 + (size_t)n * AZS);
    zp[0] = make_float4(fs[0], fs[1], fs[2], 0.f);
#pragma unroll
    for (int i = 0; i < 6; ++i)
        zp[1 + i] = make_float4(z[4*i], z[4*i+1], z[4*i+2], z[4*i+3]);
    zp[7] = make_float4(0.f, 0.f, 0.f, 0.f);
    f1d[n] = make_float4(fd[0], fd[1], fd[2], 0.f);
}

// ---------------- bucket partition (radix by dst>>5) ----------------
__global__ void k_zero(int* __restrict__ p, int n) {
    int i = blockIdx.x * blockDim.x + threadIdx.x;
    if (i < n) p[i] = 0;
}

__global__ __launch_bounds__(256) void k_count(const int* __restrict__ dst,
                                               int* __restrict__ bcnt, int E, int NB) {
    __shared__ int lh[NBMAX];
    for (int i = threadIdx.x; i < NB; i += 256) lh[i] = 0;
    __syncthreads();
    int base = blockIdx.x * PCHUNK;
    int end = base + PCHUNK; if (end > E) end = E;
    for (int i = base + threadIdx.x; i < end; i += 256)
        atomicAdd(&lh[dst[i] >> BSH], 1);
    __syncthreads();
    for (int i = threadIdx.x; i < NB; i += 256)
        if (lh[i]) atomicAdd(&bcnt[i], lh[i]);
}

#define SCANK 13   // 256*13 = 3328 >= NBMAX
__global__ __launch_bounds__(256) void k_bscan(const int* __restrict__ bcnt,
                                               int* __restrict__ boff,
                                               int* __restrict__ bcur,
                                               int* __restrict__ rowptr,
                                               int NB, int N, int E) {
    __shared__ int sd[256];
    int tid = threadIdx.x;
    int v[SCANK]; int tsum = 0;
#pragma unroll
    for (int i = 0; i < SCANK; ++i) {
        int g = tid * SCANK + i;
        v[i] = (g < NB) ? bcnt[g] : 0;
        tsum += v[i];
    }
    sd[tid] = tsum; __syncthreads();
    for (int off = 1; off < 256; off <<= 1) {
        int t = (tid >= off) ? sd[tid - off] : 0;
        __syncthreads();
        sd[tid] += t;
        __syncthreads();
    }
    int pref = sd[tid] - tsum;
#pragma unroll
    for (int i = 0; i < SCANK; ++i) {
        int g = tid * SCANK + i;
        if (g < NB) { boff[g] = pref; bcur[g] = pref; pref += v[i]; }
    }
    if (tid == 255) boff[NB] = pref;
    if (tid == 0) rowptr[N] = E;
}

__global__ __launch_bounds__(256) void k_part(const int* __restrict__ src,
                                              const int* __restrict__ dst,
                                              int* __restrict__ bcur,
                                              int* __restrict__ bedges, int E, int NB) {
    __shared__ int lh[NBMAX];
    __shared__ int lbase[NBMAX];
    for (int i = threadIdx.x; i < NB; i += 256) lh[i] = 0;
    __syncthreads();
    int base = blockIdx.x * PCHUNK;
    int end = base + PCHUNK; if (end > E) end = E;
    for (int i = base + threadIdx.x; i < end; i += 256)
        atomicAdd(&lh[dst[i] >> BSH], 1);
    __syncthreads();
    for (int i = threadIdx.x; i < NB; i += 256) {
        int c = lh[i];
        lbase[i] = c ? atomicAdd(&bcur[i], c) : 0;
        lh[i] = 0;
    }
    __syncthreads();
    for (int i = base + threadIdx.x; i < end; i += 256) {
        int d = dst[i];
        int b = d >> BSH;
        int p = lbase[b] + atomicAdd(&lh[b], 1);
        bedges[p] = src[i] | ((d & (BNODES - 1)) << 17);
    }
}

// --------- GAT layer 1: sort bucket in LDS, 8 threads/node, register acc ---------
__global__ __launch_bounds__(256) void k_gat1(
    const int* __restrict__ boff, int* __restrict__ bedges,
    const float* __restrict__ az1, const float4* __restrict__ f1d,
    const float* __restrict__ W2g, const float* __restrict__ a2g,
    float* __restrict__ z2, float* __restrict__ f2s, float* __restrict__ f2d,
    int* __restrict__ rowptr, int N) {
    __shared__ int ssrc[SCAP];
    __shared__ int scnt[BNODES];
    __shared__ int sstart[BNODES + 1];
    __shared__ int scur[BNODES];
    __shared__ float sW2[C1 * C2];
    __shared__ float sa2[2 * C2];
    int tid = threadIdx.x;
    int b = blockIdx.x;
    int beg = boff[b], cnt = boff[b + 1] - beg;
    if (tid < BNODES) scnt[tid] = 0;
    for (int i = tid; i < C1 * C2; i += 256) sW2[i] = W2g[i];
    if (tid < 2 * C2) sa2[tid] = a2g[tid];
    __syncthreads();
    // count
    for (int i = tid; i < cnt; i += 256)
        atomicAdd(&scnt[bedges[beg + i] >> 17], 1);
    __syncthreads();
    // exclusive scan over 32 counters (lanes 0-31 of wave 0)
    if (tid < BNODES) {
        int v = scnt[tid];
        int x = v;
        for (int d = 1; d < BNODES; d <<= 1) {
            int t = __shfl_up(x, d, 64);
            if (tid >= d) x += t;
        }
        sstart[tid] = x - v;
        scur[tid] = x - v;
        if (tid == BNODES - 1) sstart[BNODES] = x;
    }
    __syncthreads();
    // place (counting sort)
    for (int i = tid; i < cnt; i += 256) {
        int pk = bedges[beg + i];
        int p = atomicAdd(&scur[pk >> 17], 1);
        ssrc[p] = pk & 0x1FFFF;
    }
    __syncthreads();
    // write sorted CSR back in-place + rowptr
    for (int i = tid; i < cnt; i += 256) bedges[beg + i] = ssrc[i];
    int n0 = b << BSH;
    if (tid < BNODES) rowptr[n0 + tid] = beg + sstart[tid];
    // aggregate: 8 threads per node
    int nl = tid >> 3, l8 = tid & 7;
    int n = n0 + nl;
    int s0 = sstart[nl], s1 = sstart[nl + 1];
    float4 fdv = (n < N) ? f1d[n] : make_float4(0.f, 0.f, 0.f, 0.f);
    float acc[C1];
#pragma unroll
    for (int c = 0; c < C1; ++c) acc[c] = 0.f;
    float den0 = 0.f, den1 = 0.f, den2 = 0.f;
    for (int i = s0 + l8; i < s1; i += 8) {
        int s = ssrc[i];
        const float4* zp = (const float4*)(az1 + ((size_t)s << 5));
        float4 q0 = zp[0], q1 = zp[1], q2 = zp[2], q3 = zp[3],
               q4 = zp[4], q5 = zp[5], q6 = zp[6];
        float e0 = q0.x + fdv.x, e1 = q0.y + fdv.y, e2 = q0.z + fdv.z;
        e0 = e0 > 0.f ? e0 : 0.01f * e0;
        e1 = e1 > 0.f ? e1 : 0.01f * e1;
        e2 = e2 > 0.f ? e2 : 0.01f * e2;
        float a0 = __expf(e0), a1 = __expf(e1), a2v = __expf(e2);
        den0 += a0; den1 += a1; den2 += a2v;
        acc[0]  += a0 * q1.x; acc[1]  += a0 * q1.y; acc[2]  += a0 * q1.z; acc[3]  += a0 * q1.w;
        acc[4]  += a0 * q2.x; acc[5]  += a0 * q2.y; acc[6]  += a0 * q2.z; acc[7]  += a0 * q2.w;
        acc[8]  += a1 * q3.x; acc[9]  += a1 * q3.y; acc[10] += a1 * q3.z; acc[11] += a1 * q3.w;
        acc[12] += a1 * q4.x; acc[13] += a1 * q4.y; acc[14] += a1 * q4.z; acc[15] += a1 * q4.w;
        acc[16] += a2v * q5.x; acc[17] += a2v * q5.y; acc[18] += a2v * q5.z; acc[19] += a2v * q5.w;
        acc[20] += a2v * q6.x; acc[21] += a2v * q6.y; acc[22] += a2v * q6.z; acc[23] += a2v * q6.w;
    }
    // combine the 8 threads of each node (lanes 8k..8k+7, same wave)
#pragma unroll
    for (int c = 0; c < C1; ++c) {
        acc[c] += __shfl_xor(acc[c], 1, 64);
        acc[c] += __shfl_xor(acc[c], 2, 64);
        acc[c] += __shfl_xor(acc[c], 4, 64);
    }
    den0 += __shfl_xor(den0, 1, 64); den0 += __shfl_xor(den0, 2, 64); den0 += __shfl_xor(den0, 4, 64);
    den1 += __shfl_xor(den1, 1, 64); den1 += __shfl_xor(den1, 2, 64); den1 += __shfl_xor(den1, 4, 64);
    den2 += __shfl_xor(den2, 1, 64); den2 += __shfl_xor(den2, 2, 64); den2 += __shfl_xor(den2, 4, 64);
    if (l8 == 0 && n < N) {
        float h1v[C1];
        float inv0 = 1.f / den0, inv1 = 1.f / den1, inv2 = 1.f / den2;
#pragma unroll
        for (int o = 0; o < HID; ++o) {
            float v0 = acc[o] * inv0;
            float v1 = acc[HID + o] * inv1;
            float v2 = acc[2 * HID + o] * inv2;
            h1v[o]           = v0 > 0.f ? v0 : (__expf(v0) - 1.f);
            h1v[HID + o]     = v1 > 0.f ? v1 : (__expf(v1) - 1.f);
            h1v[2 * HID + o] = v2 > 0.f ? v2 : (__expf(v2) - 1.f);
        }
        float zz[C2];
#pragma unroll
        for (int k = 0; k < C2; ++k) zz[k] = 0.f;
        for (int c = 0; c < C1; ++c) {
            float hv = h1v[c];
#pragma unroll
            for (int k = 0; k < C2; ++k) zz[k] += hv * sW2[c * C2 + k];
        }
        float fs = 0.f, fdd = 0.f;
#pragma unroll
        for (int k = 0; k < C2; ++k) {
            fs  += zz[k] * sa2[k];
            fdd += zz[k] * sa2[C2 + k];
        }
        float4* zo = (float4*)(z2 + (size_t)n * C2);
#pragma unroll
        for (int i = 0; i < 4; ++i)
            zo[i] = make_float4(zz[4*i], zz[4*i+1], zz[4*i+2], zz[4*i+3]);
        f2s[n] = fs;
        f2d[n] = fdd;
    }
}

// --------- GAT layer 2: CSR, 8 threads/node, register acc ---------
__global__ __launch_bounds__(256) void k_gat2(
    const int* __restrict__ rowptr, const int* __restrict__ csr,
    const float* __restrict__ z2, const float* __restrict__ f2s,
    const float* __restrict__ f2d, float* __restrict__ item, int N) {
    int t = blockIdx.x * blockDim.x + threadIdx.x;
    int n = t >> 3, l8 = t & 7;
    if (n >= N) return;
    int beg = rowptr[n], end = rowptr[n + 1];
    float fdv = f2d[n];
    float acc[C2];
#pragma unroll
    for (int k = 0; k < C2; ++k) acc[k] = 0.f;
    float den = 0.f;
    for (int i = beg + l8; i < end; i += 8) {
        int s = csr[i];
        float e = f2s[s] + fdv;
        e = e > 0.f ? e : 0.01f * e;
        float a = __expf(e);
        den += a;
        const float4* zp = (const float4*)(z2 + (size_t)s * C2);
        float4 q0 = zp[0], q1 = zp[1], q2 = zp[2], q3 = zp[3];
        acc[0]  += a * q0.x; acc[1]  += a * q0.y; acc[2]  += a * q0.z; acc[3]  += a * q0.w;
        acc[4]  += a * q1.x; acc[5]  += a * q1.y; acc[6]  += a * q1.z; acc[7]  += a * q1.w;
        acc[8]  += a * q2.x; acc[9]  += a * q2.y; acc[10] += a * q2.z; acc[11] += a * q2.w;
        acc[12] += a * q3.x; acc[13] += a * q3.y; acc[14] += a * q3.z; acc[15] += a * q3.w;
    }
#pragma unroll
    for (int k = 0; k < C2; ++k) {
        acc[k] += __shfl_xor(acc[k], 1, 64);
        acc[k] += __shfl_xor(acc[k], 2, 64);
        acc[k] += __shfl_xor(acc[k], 4, 64);
    }
    den += __shfl_xor(den, 1, 64);
    den += __shfl_xor(den, 2, 64);
    den += __shfl_xor(den, 4, 64);
    if (l8 == 0) {
        float inv = 1.f / den;
        float4* io = (float4*)(item + (size_t)n * C2);
#pragma unroll
        for (int i = 0; i < 4; ++i)
            io[i] = make_float4(acc[4*i]*inv, acc[4*i+1]*inv, acc[4*i+2]*inv, acc[4*i+3]*inv);
    }
}

// ---------------- query pooling: one block per query row ----------------
__global__ __launch_bounds__(256) void k_query(
    const float* __restrict__ queries, const float* __restrict__ item,
    float* __restrict__ out, int N) {
    int b = blockIdx.x;
    const float4* qrow = (const float4*)(queries + (size_t)b * N);
    int n4 = N >> 2;
    float acc[C2];
#pragma unroll
    for (int k = 0; k < C2; ++k) acc[k] = 0.f;
    float cnt = 0.f;
    for (int i = threadIdx.x; i < n4; i += 256) {
        float4 v = qrow[i];
        int j = i * 4;
        float vv[4] = {v.x, v.y, v.z, v.w};
#pragma unroll
        for (int c = 0; c < 4; ++c) {
            if (vv[c] != 0.f) {
                cnt += vv[c];
                const float4* rp = (const float4*)(item + (size_t)(j + c) * C2);
                float4 r0 = rp[0], r1 = rp[1], r2 = rp[2], r3 = rp[3];
                acc[0]  += vv[c]*r0.x; acc[1]  += vv[c]*r0.y; acc[2]  += vv[c]*r0.z; acc[3]  += vv[c]*r0.w;
                acc[4]  += vv[c]*r1.x; acc[5]  += vv[c]*r1.y; acc[6]  += vv[c]*r1.z; acc[7]  += vv[c]*r1.w;
                acc[8]  += vv[c]*r2.x; acc[9]  += vv[c]*r2.y; acc[10] += vv[c]*r2.z; acc[11] += vv[c]*r2.w;
                acc[12] += vv[c]*r3.x; acc[13] += vv[c]*r3.y; acc[14] += vv[c]*r3.z; acc[15] += vv[c]*r3.w;
            }
        }
    }
    int rem = N & 3;
    if ((int)threadIdx.x < rem) {
        int j = n4 * 4 + threadIdx.x;
        float qv = queries[(size_t)b * N + j];
        if (qv != 0.f) {
            cnt += qv;
#pragma unroll
            for (int k = 0; k < C2; ++k) acc[k] += qv * item[(size_t)j * C2 + k];
        }
    }
    __shared__ float red[4][C2 + 1];
    int lane = threadIdx.x & 63, wid = threadIdx.x >> 6;
#pragma unroll
    for (int k = 0; k < C2; ++k)
        for (int off = 32; off; off >>= 1) acc[k] += __shfl_down(acc[k], off, 64);
    for (int off = 32; off; off >>= 1) cnt += __shfl_down(cnt, off, 64);
    if (lane == 0) {
#pragma unroll
        for (int k = 0; k < C2; ++k) red[wid][k] = acc[k];
        red[wid][C2] = cnt;
    }
    __syncthreads();
    if (threadIdx.x < C2 + 1) {
        float s = red[0][threadIdx.x] + red[1][threadIdx.x] +
                  red[2][threadIdx.x] + red[3][threadIdx.x];
        red[0][threadIdx.x] = s;
    }
    __syncthreads();
    if (threadIdx.x < C2)
        out[(size_t)b * C2 + threadIdx.x] = red[0][threadIdx.x] / red[0][C2];
}

// ---------------- pos/neg gathers ----------------
__global__ void k_posneg(const int* __restrict__ pos, const int* __restrict__ neg,
                         const float* __restrict__ item, float* __restrict__ out, int B) {
    int idx = blockIdx.x * blockDim.x + threadIdx.x;
    int total = 2 * B * C2;
    if (idx >= total) return;
    int which = idx / (B * C2);
    int r = idx - which * B * C2;
    int b = r / C2, k = r - b * C2;
    int node = which ? neg[b] : pos[b];
    out[(size_t)B * C2 + idx] = item[(size_t)node * C2 + k];
}

extern "C" void kernel_launch(void* const* d_in, const int* in_sizes, int n_in,
                              void* d_out, int out_size, void* d_ws, size_t ws_size,
                              hipStream_t stream) {
    const float* queries = (const float*)d_in[0];
    const int*   pos     = (const int*)d_in[1];
    const int*   neg     = (const int*)d_in[2];
    const float* emb     = (const float*)d_in[3];
    const float* W1      = (const float*)d_in[4];
    const float* a1      = (const float*)d_in[5];
    const float* W2      = (const float*)d_in[6];
    const float* a2      = (const float*)d_in[7];
    const int*   src     = (const int*)d_in[8];
    const int*   dst     = (const int*)d_in[9];

    int B = in_sizes[1];
    int N = in_sizes[3] / 64;
    int E = in_sizes[8];
    float* out = (float*)d_out;

    int NB = (N + BNODES - 1) >> BSH;

    char* w = (char*)d_ws;
    auto alloc = [&](size_t bytes) -> char* {
        char* p = w;
        w += (bytes + 255) & ~(size_t)255;
        return p;
    };
    float*  az1    = (float*)alloc(sizeof(float) * (size_t)N * AZS);
    float4* f1d    = (float4*)alloc(sizeof(float4) * (size_t)N);
    float*  z2     = (float*)alloc(sizeof(float) * (size_t)N * C2);
    float*  f2s    = (float*)alloc(sizeof(float) * (size_t)N);
    float*  f2d    = (float*)alloc(sizeof(float) * (size_t)N);
    float*  item   = (float*)alloc(sizeof(float) * (size_t)N * C2);
    int*    bcnt   = (int*)alloc(sizeof(int) * (size_t)NB);
    int*    boff   = (int*)alloc(sizeof(int) * (size_t)(NB + 1));
    int*    bcur   = (int*)alloc(sizeof(int) * (size_t)NB);
    int*    rowptr = (int*)alloc(sizeof(int) * (size_t)(N + 1));
    int*    bedges = (int*)alloc(sizeof(int) * (size_t)E);

    int nblkN = (N + 255) / 256;
    int nPart = (E + PCHUNK - 1) / PCHUNK;

    k_z1<<<nblkN, 256, 0, stream>>>(emb, W1, a1, az1, f1d, N);
    k_zero<<<(NB + 255) / 256, 256, 0, stream>>>(bcnt, NB);
    k_count<<<nPart, 256, 0, stream>>>(dst, bcnt, E, NB);
    k_bscan<<<1, 256, 0, stream>>>(bcnt, boff, bcur, rowptr, NB, N, E);
    k_part<<<nPart, 256, 0, stream>>>(src, dst, bcur, bedges, E, NB);
    k_gat1<<<NB, 256, 0, stream>>>(boff, bedges, az1, f1d, W2, a2,
                                   z2, f2s, f2d, rowptr, N);
    k_gat2<<<(N * 8 + 255) / 256, 256, 0, stream>>>(rowptr, bedges, z2, f2s, f2d, item, N);
    k_query<<<B, 256, 0, stream>>>(queries, item, out, N);
    k_posneg<<<(2 * B * C2 + 255) / 256, 256, 0, stream>>>(pos, neg, item, out, B);
}